// Round 8
// baseline (84.523 us; speedup 1.0000x reference)
//
#include <hip/hip_runtime.h>

// 2-layer dense GAT, B=32, N=1024, fp32, FUSED one launch, ~58 KB LDS.
// L1: H=3,F=4,O=2; L2: H=1,F=6,O=4. One block per batch b (32 blocks x 1024 thr).
//
// Round-17: R7 (no float atomics) put the kernel at ~21 us (below the 40 us
// fills). Still phase/latency-bound: 12 barrier-separated phases. This round
// fuses the segmented-reduce (P5) INTO the scan jobs (P6): each one-wave scan
// computes its own per-bucket sums directly from the rank-sorted (key,wh)
// arrays (4 buckets/lane, exp2 on the fly), so the raw bucket-sum LDS
// round-trip, its barrier, and the sentinel sub-phases all disappear.
// 12 -> 10 barriers; math identical (same summation order per bucket).
//
// Algorithm (verified R10-R16): LeakyReLU(e) piecewise-linear in s_src+s_dst:
//   w(n,m) = rho(n)*E1(m)  if s_dst[m] > -s_src[n]  (rho=e^{0.8 s_src}, E1=e^{s_dst})
//          = E2(m)         otherwise                 (E2=e^{0.2 s_dst})
// Bucket s_dst into NB=256 bins (rank-scatter, int atomic only); one-wave
// fused sum+scan jobs produce prefix(E2-family)/suffix(E1-family) arrays;
// each row = O(1) lookup + exact max(rho*E1,E2) sweep over its boundary
// bucket. Monotone quantizer => partition exact; boundary max-form exact.

#define GAT_ALPHA 0.2f
#define LOG2E 1.44269504088896f

__device__ __forceinline__ float ex2(float v) { return __builtin_amdgcn_exp2f(v); }

constexpr int N = 1024, NT = 1024, NW = NT / 64, NB = 256, BPL = NB / 64;
constexpr int WCS = NB + 1;

// L1 per-head region (float words): cs[257](int) | key[1024] | wh0[1024] | wh1[1024]
//                                  | pre[3*257] | suf[3*257]
constexpr int OFF_KEY = WCS;                    // 257
constexpr int OFF_WH0 = OFF_KEY + N;            // 1281
constexpr int OFF_WH1 = OFF_WH0 + N;            // 2305
constexpr int OFF_PRE = OFF_WH1 + N;            // 3329
constexpr int OFF_SUF = OFF_PRE + 3 * WCS;      // 4100
constexpr int L1_HEAD = OFF_SUF + 3 * WCS;      // 4871
constexpr int SMEM_WORDS = 3 * L1_HEAD;         // 14613 words = 58.4 KB

// L2 aliased at smem base: key2[1024] | wh2[4*1024] | pre2[5*257] | suf2[5*257]
constexpr int OFF2_KEY = 0;
constexpr int OFF2_WHS = N;                     // 1024
constexpr int OFF2_PRE = OFF2_WHS + 4 * N;      // 5120
constexpr int OFF2_SUF = OFF2_PRE + 5 * WCS;    // 6405
constexpr int L2_TOTAL = OFF2_SUF + 5 * WCS;    // 7690
static_assert(L2_TOTAL <= SMEM_WORDS, "L2 must alias inside L1 region");

// ---- one-wave int scan over NB buckets (counts -> exclusive starts) ----
__device__ __forceinline__ void wave_scan_int(int* a, int ln) {
    int c[BPL];
#pragma unroll
    for (int i = 0; i < BPL; ++i) c[i] = a[ln * BPL + i];
    int s = 0;
#pragma unroll
    for (int i = 0; i < BPL; ++i) s += c[i];
    int run = s;
#pragma unroll
    for (int d = 1; d < 64; d <<= 1) {
        const int u = __shfl_up(run, d, 64);
        if (ln >= d) run += u;
    }
    int acc = run - s;
#pragma unroll
    for (int i = 0; i < BPL; ++i) { const int t = acc; acc += c[i]; a[ln * BPL + i] = t; }
    if (ln == 63) a[NB] = run;                   // total (= N)
}

// ---- fused one-wave jobs: per-bucket sum from sorted arrays + scan ----
// pre: dst[q] = sum over buckets < q of S(bucket);  (exclusive prefix)
// suf: dst[q] = sum over buckets >= q; dst[NB] = 0. (inclusive suffix)
// S(bucket) = sum over its elements of ex2(escale*key) * (HASMUL ? mul : 1)
template <bool HASMUL>
__device__ __forceinline__ void scan_job_pre(const int* cs, const float* keys,
                                             const float* mul, float escale,
                                             float* dst, int ln) {
    float v[BPL];
#pragma unroll
    for (int i = 0; i < BPL; ++i) {
        const int q = ln * BPL + i;
        const int i0 = cs[q], i1 = cs[q + 1];
        float s = 0.0f;
        for (int j = i0; j < i1; ++j) {
            const float e = ex2(escale * keys[j]);
            s += HASMUL ? e * mul[j] : e;
        }
        v[i] = s;
    }
    float s = 0.0f;
#pragma unroll
    for (int i = 0; i < BPL; ++i) s += v[i];
    float run = s;
#pragma unroll
    for (int d = 1; d < 64; d <<= 1) {
        const float u = __shfl_up(run, d, 64);
        if (ln >= d) run += u;
    }
    float acc = run - s;                         // sum over lanes < ln
#pragma unroll
    for (int i = 0; i < BPL; ++i) { const float t = acc; acc += v[i]; dst[ln * BPL + i] = t; }
}
template <bool HASMUL>
__device__ __forceinline__ void scan_job_suf(const int* cs, const float* keys,
                                             const float* mul, float escale,
                                             float* dst, int ln) {
    float v[BPL];
#pragma unroll
    for (int i = 0; i < BPL; ++i) {
        const int q = ln * BPL + i;
        const int i0 = cs[q], i1 = cs[q + 1];
        float s = 0.0f;
        for (int j = i0; j < i1; ++j) {
            const float e = ex2(escale * keys[j]);
            s += HASMUL ? e * mul[j] : e;
        }
        v[i] = s;
    }
    float s = 0.0f;
#pragma unroll
    for (int i = 0; i < BPL; ++i) s += v[i];
    float run = s;
#pragma unroll
    for (int d = 1; d < 64; d <<= 1) {
        const float u = __shfl_down(run, d, 64);
        if (ln < 64 - d) run += u;
    }
    float acc = run - s;                         // sum over lanes > ln
#pragma unroll
    for (int i = BPL - 1; i >= 0; --i) { acc += v[i]; dst[ln * BPL + i] = acc; }
    if (ln == 63) dst[NB] = 0.0f;                // sentinel for bq = NB-1
}

__global__ __launch_bounds__(NT) void gat_fused(
    const float* __restrict__ x,    // (32,1024,4)
    const float* __restrict__ W1,   // (3,4,2)
    const float* __restrict__ a1,   // (3,4)
    const float* __restrict__ W2,   // (6,4)
    const float* __restrict__ a2,   // (8)
    float* __restrict__ out)        // (32,1024,4)
{
    __shared__ __align__(16) float smem[SMEM_WORDS];
    __shared__ int   cs2[WCS];      // L2 counts/starts (not aliased)
    __shared__ float sMM[4][2 * NW];

    const int b   = blockIdx.x;
    const int tid = threadIdx.x, wv = tid >> 6, ln = tid & 63;
    const int m   = tid;            // one element / one row per thread

    // ---- uniform weights ----
    float Wl1[3][4][2], as1[3][2], ad1[3][2];
#pragma unroll
    for (int hh = 0; hh < 3; ++hh) {
#pragma unroll
        for (int f = 0; f < 4; ++f)
#pragma unroll
            for (int o = 0; o < 2; ++o) Wl1[hh][f][o] = W1[(hh * 4 + f) * 2 + o];
#pragma unroll
        for (int o = 0; o < 2; ++o) {
            as1[hh][o] = a1[hh * 4 + o];
            ad1[hh][o] = a1[hh * 4 + 2 + o];
        }
    }
    float Wl2[6][4], as2[4], ad2[4];
#pragma unroll
    for (int f = 0; f < 6; ++f)
#pragma unroll
        for (int o = 0; o < 4; ++o) Wl2[f][o] = W2[f * 4 + o];
#pragma unroll
    for (int o = 0; o < 4; ++o) { as2[o] = a2[o]; ad2[o] = a2[4 + o]; }

    // ---- zero count arrays (ints only; everything else is write-once) ----
    if (tid < WCS) {
#pragma unroll
        for (int hh = 0; hh < 3; ++hh) ((int*)(smem + hh * L1_HEAD))[tid] = 0;
        cs2[tid] = 0;
    }

    // ================= LAYER 1 =================
    // P1: Wh, key=s_dst, s_src (regs); per-head block min/max
    const float4 xr = ((const float4*)(x + (size_t)b * N * 4))[m];
    float key1[3], sn1[3], wh1[3][2];
#pragma unroll
    for (int hh = 0; hh < 3; ++hh) {
        const float w0 = xr.x * Wl1[hh][0][0] + xr.y * Wl1[hh][1][0] +
                         xr.z * Wl1[hh][2][0] + xr.w * Wl1[hh][3][0];
        const float w1 = xr.x * Wl1[hh][0][1] + xr.y * Wl1[hh][1][1] +
                         xr.z * Wl1[hh][2][1] + xr.w * Wl1[hh][3][1];
        wh1[hh][0] = w0; wh1[hh][1] = w1;
        key1[hh] = w0 * ad1[hh][0] + w1 * ad1[hh][1];
        sn1[hh]  = w0 * as1[hh][0] + w1 * as1[hh][1];
        float mn = key1[hh], mx = key1[hh];
#pragma unroll
        for (int d = 1; d < 64; d <<= 1) {
            mn = fminf(mn, __shfl_xor(mn, d, 64));
            mx = fmaxf(mx, __shfl_xor(mx, d, 64));
        }
        if (ln == 0) { sMM[hh][wv] = mn; sMM[hh][NW + wv] = mx; }
    }
    __syncthreads();   // bar 1: zeros + sMM

    float kmin1[3], invw1[3];
#pragma unroll
    for (int hh = 0; hh < 3; ++hh) {
        float mn = sMM[hh][0], mx = sMM[hh][NW];
#pragma unroll
        for (int w = 1; w < NW; ++w) {
            mn = fminf(mn, sMM[hh][w]);
            mx = fmaxf(mx, sMM[hh][NW + w]);
        }
        kmin1[hh] = mn;
        invw1[hh] = (float)NB / fmaxf(mx - mn, 1e-30f);
    }

    // P2: bucket + rank (native int LDS atomic only)
    int bk1[3], rk1[3];
#pragma unroll
    for (int hh = 0; hh < 3; ++hh) {
        int q = (int)((key1[hh] - kmin1[hh]) * invw1[hh]);
        q = q < 0 ? 0 : (q > NB - 1 ? NB - 1 : q);
        bk1[hh] = q;
        rk1[hh] = atomicAdd((int*)(smem + hh * L1_HEAD) + q, 1);
    }
    __syncthreads();   // bar 2

    // P3: int scans -> exclusive starts (3 one-wave jobs)
    if (wv < 3) wave_scan_int((int*)(smem + wv * L1_HEAD), ln);
    __syncthreads();   // bar 3

    // P4: rank-scatter values (key, wh0, wh1)
#pragma unroll
    for (int hh = 0; hh < 3; ++hh) {
        float* bp = smem + hh * L1_HEAD;
        const int pos = ((int*)bp)[bk1[hh]] + rk1[hh];
        bp[OFF_KEY + pos] = key1[hh];
        bp[OFF_WH0 + pos] = wh1[hh][0];
        bp[OFF_WH1 + pos] = wh1[hh][1];
    }
    __syncthreads();   // bar 4

    // P5: fused sum+scan, 18 one-wave jobs (3 heads x [3 pre | 3 suf])
    for (int job = wv; job < 18; job += NW) {
        const int hh = job / 6, r = job % 6;
        float* bp = smem + hh * L1_HEAD;
        const int* cs = (const int*)bp;
        const float* keys = bp + OFF_KEY;
        switch (r) {
        case 0: scan_job_pre<false>(cs, keys, nullptr,      GAT_ALPHA * LOG2E, bp + OFF_PRE,           ln); break;
        case 1: scan_job_pre<true >(cs, keys, bp + OFF_WH0, GAT_ALPHA * LOG2E, bp + OFF_PRE + WCS,     ln); break;
        case 2: scan_job_pre<true >(cs, keys, bp + OFF_WH1, GAT_ALPHA * LOG2E, bp + OFF_PRE + 2 * WCS, ln); break;
        case 3: scan_job_suf<false>(cs, keys, nullptr,      LOG2E,             bp + OFF_SUF,           ln); break;
        case 4: scan_job_suf<true >(cs, keys, bp + OFF_WH0, LOG2E,             bp + OFF_SUF + WCS,     ln); break;
        default:scan_job_suf<true >(cs, keys, bp + OFF_WH1, LOG2E,             bp + OFF_SUF + 2 * WCS, ln); break;
        }
    }
    __syncthreads();   // bar 5

    // P6: rows -> h1 (registers); L2 phase-1 folded in (sMM[3])
    float hv[6];
#pragma unroll
    for (int hh = 0; hh < 3; ++hh) {
        float* bp = smem + hh * L1_HEAD;
        const int* cs = (const int*)bp;
        const float sn = sn1[hh];
        const float rho = ex2(0.8f * LOG2E * sn);
        int bq = (int)((-sn - kmin1[hh]) * invw1[hh]);
        bq = bq < 0 ? 0 : (bq > NB - 1 ? NB - 1 : bq);
        const int i0 = cs[bq], i1 = cs[bq + 1];
        float den = rho * bp[OFF_SUF + bq + 1] + bp[OFF_PRE + bq];
        float n0  = rho * bp[OFF_SUF + WCS + bq + 1] + bp[OFF_PRE + WCS + bq];
        float n1  = rho * bp[OFF_SUF + 2 * WCS + bq + 1] + bp[OFF_PRE + 2 * WCS + bq];
        for (int i = i0; i < i1; ++i) {          // boundary bucket: exact max-form
            const float kk = bp[OFF_KEY + i];
            const float w = fmaxf(rho * ex2(LOG2E * kk), ex2(GAT_ALPHA * LOG2E * kk));
            den += w;
            n0 += w * bp[OFF_WH0 + i];
            n1 += w * bp[OFF_WH1 + i];
        }
        float v0 = n0 / den, v1 = n1 / den;
        hv[hh * 2]     = (v0 > 0.0f) ? v0 : (__expf(v0) - 1.0f);
        hv[hh * 2 + 1] = (v1 > 0.0f) ? v1 : (__expf(v1) - 1.0f);
    }
    // L2 P1: wh2/key2/sn2 from register h1 + minmax
    float key2, sn2, wh2[4];
    {
        float kd = 0.0f, sn = 0.0f;
#pragma unroll
        for (int o = 0; o < 4; ++o) {
            float acc = 0.0f;
#pragma unroll
            for (int f = 0; f < 6; ++f) acc += hv[f] * Wl2[f][o];
            wh2[o] = acc;
            kd += acc * ad2[o];
            sn += acc * as2[o];
        }
        key2 = kd; sn2 = sn;
        float mn = kd, mx = kd;
#pragma unroll
        for (int d = 1; d < 64; d <<= 1) {
            mn = fminf(mn, __shfl_xor(mn, d, 64));
            mx = fmaxf(mx, __shfl_xor(mx, d, 64));
        }
        if (ln == 0) { sMM[3][wv] = mn; sMM[3][NW + wv] = mx; }
    }
    __syncthreads();   // bar 6: L1 arrays dead; sMM[3] ready; cs2 pre-zeroed

    // ================= LAYER 2 (aliased; h1 register-only) =================
    float kmin2, invw2;
    {
        float mn = sMM[3][0], mx = sMM[3][NW];
#pragma unroll
        for (int w = 1; w < NW; ++w) {
            mn = fminf(mn, sMM[3][w]);
            mx = fmaxf(mx, sMM[3][NW + w]);
        }
        kmin2 = mn;
        invw2 = (float)NB / fmaxf(mx - mn, 1e-30f);
    }

    // P2': bucket + rank
    int bk2, rk2;
    {
        int q = (int)((key2 - kmin2) * invw2);
        q = q < 0 ? 0 : (q > NB - 1 ? NB - 1 : q);
        bk2 = q;
        rk2 = atomicAdd(cs2 + q, 1);
    }
    __syncthreads();   // bar 7

    // P3': int scan
    if (wv == 0) wave_scan_int(cs2, ln);
    __syncthreads();   // bar 8

    // P4': scatter key + wh
    {
        const int pos = cs2[bk2] + rk2;
        smem[OFF2_KEY + pos] = key2;
#pragma unroll
        for (int o = 0; o < 4; ++o) smem[OFF2_WHS + o * N + pos] = wh2[o];
    }
    __syncthreads();   // bar 9

    // P5': fused sum+scan, 10 one-wave jobs
    if (wv < 10) {
        const float* keys = smem + OFF2_KEY;
        if (wv == 0)     scan_job_pre<false>(cs2, keys, nullptr, GAT_ALPHA * LOG2E, smem + OFF2_PRE, ln);
        else if (wv < 5) scan_job_pre<true >(cs2, keys, smem + OFF2_WHS + (wv - 1) * N,
                                             GAT_ALPHA * LOG2E, smem + OFF2_PRE + wv * WCS, ln);
        else if (wv == 5) scan_job_suf<false>(cs2, keys, nullptr, LOG2E, smem + OFF2_SUF, ln);
        else              scan_job_suf<true >(cs2, keys, smem + OFF2_WHS + (wv - 6) * N,
                                              LOG2E, smem + OFF2_SUF + (wv - 5) * WCS, ln);
    }
    __syncthreads();   // bar 10

    // P6': rows -> out (float4)
    {
        const float rho = ex2(0.8f * LOG2E * sn2);
        int bq = (int)((-sn2 - kmin2) * invw2);
        bq = bq < 0 ? 0 : (bq > NB - 1 ? NB - 1 : bq);
        const int i0 = cs2[bq], i1 = cs2[bq + 1];
        float den = rho * smem[OFF2_SUF + bq + 1] + smem[OFF2_PRE + bq];
        float num[4];
#pragma unroll
        for (int o = 0; o < 4; ++o)
            num[o] = rho * smem[OFF2_SUF + (1 + o) * WCS + bq + 1] +
                     smem[OFF2_PRE + (1 + o) * WCS + bq];
        for (int i = i0; i < i1; ++i) {          // boundary bucket: exact max-form
            const float kk = smem[OFF2_KEY + i];
            const float w = fmaxf(rho * ex2(LOG2E * kk), ex2(GAT_ALPHA * LOG2E * kk));
            den += w;
#pragma unroll
            for (int o = 0; o < 4; ++o) num[o] += w * smem[OFF2_WHS + o * N + i];
        }
        float vv[4];
#pragma unroll
        for (int o = 0; o < 4; ++o) {
            float v = num[o] / den;
            vv[o] = (v > 0.0f) ? v : (__expf(v) - 1.0f);
        }
        float4 yv;
        yv.x = vv[0]; yv.y = vv[1]; yv.z = vv[2]; yv.w = vv[3];
        ((float4*)out)[(size_t)b * N + m] = yv;
    }
}

extern "C" void kernel_launch(void* const* d_in, const int* in_sizes, int n_in,
                              void* d_out, int out_size, void* d_ws, size_t ws_size,
                              hipStream_t stream) {
    const float* x  = (const float*)d_in[0];  // (32,1024,4)
    const float* W1 = (const float*)d_in[1];  // (3,4,2)
    const float* a1 = (const float*)d_in[2];  // (3,4,1)
    const float* W2 = (const float*)d_in[3];  // (1,6,4)
    const float* a2 = (const float*)d_in[4];  // (1,8,1)
    float* y = (float*)d_out;                 // (32,1024,4)

    (void)d_ws; (void)ws_size;
    gat_fused<<<32, NT, 0, stream>>>(x, W1, a1, W2, a2, y);
}

// Round 9
// 78.593 us; speedup vs baseline: 1.0754x; 1.0754x over previous
//
#include <hip/hip_runtime.h>

// 2-layer dense GAT, B=32, N=1024, fp32, FUSED one launch, ~58 KB LDS.
// L1: H=3,F=4,O=2; L2: H=1,F=6,O=4. One block per batch b (32 blocks x 1024 thr).
//
// Round-18: R8's fused sum+scan REGRESSED (kernel ~21 -> ~26.5 us): it moved
// per-bucket summing into the scan waves (16 serial latency-exposed elements
// per lane + 6x redundant key reads). Reverted to R7's split structure
// (parallel segmented reduce -> scan over 257 sums), plus two depth cuts:
//  * scan jobs on 32-LANE GROUPS (8 buckets/lane): 18 L1 jobs = 576 lanes ->
//    ONE round (R7 needed 2 rounds on 16 waves); 10 L2 jobs likewise.
//  * L2 segmented reduce split across 512 threads by exp-family (E1|E2),
//    halving that phase's per-thread serial work.
//
// Algorithm (verified R10-R17): LeakyReLU(e) piecewise-linear in s_src+s_dst:
//   w(n,m) = rho(n)*E1(m)  if s_dst[m] > -s_src[n]  (rho=e^{0.8 s_src}, E1=e^{s_dst})
//          = E2(m)         otherwise                 (E2=e^{0.2 s_dst})
// Bucket s_dst into NB=256 bins (rank-scatter, int atomic only); parallel
// segmented reduce -> per-bucket sums {E1,E1*Wh_o}/{E2,E2*Wh_o}; group scans
// produce prefix(E2-family)/suffix(E1-family); each row = O(1) lookup + exact
// max(rho*E1,E2) sweep over its boundary bucket. Monotone quantizer =>
// partition exact; boundary max-form exact for any element.

#define GAT_ALPHA 0.2f
#define LOG2E 1.44269504088896f

__device__ __forceinline__ float ex2(float v) { return __builtin_amdgcn_exp2f(v); }

constexpr int N = 1024, NT = 1024, NW = NT / 64, NB = 256, BPL = NB / 64;
constexpr int GL = 32, BPG = NB / GL;           // 32-lane scan groups, 8 buckets/lane
constexpr int WCS = NB + 1;

// L1 per-head region (float words): cs[257](int) | key[1024] | wh0[1024] | wh1[1024]
//                                  | pre[3*257] | suf[3*257]
constexpr int OFF_KEY = WCS;                    // 257
constexpr int OFF_WH0 = OFF_KEY + N;            // 1281
constexpr int OFF_WH1 = OFF_WH0 + N;            // 2305
constexpr int OFF_PRE = OFF_WH1 + N;            // 3329
constexpr int OFF_SUF = OFF_PRE + 3 * WCS;      // 4100
constexpr int L1_HEAD = OFF_SUF + 3 * WCS;      // 4871
constexpr int SMEM_WORDS = 3 * L1_HEAD;         // 14613 words = 58.4 KB

// L2 aliased at smem base: key2[1024] | wh2[4*1024] | pre2[5*257] | suf2[5*257]
constexpr int OFF2_KEY = 0;
constexpr int OFF2_WHS = N;                     // 1024
constexpr int OFF2_PRE = OFF2_WHS + 4 * N;      // 5120
constexpr int OFF2_SUF = OFF2_PRE + 5 * WCS;    // 6405
constexpr int L2_TOTAL = OFF2_SUF + 5 * WCS;    // 7690
static_assert(L2_TOTAL <= SMEM_WORDS, "L2 must alias inside L1 region");

// ---- one-wave int scan over NB buckets (counts -> exclusive starts) ----
__device__ __forceinline__ void wave_scan_int(int* a, int ln) {
    int c[BPL];
#pragma unroll
    for (int i = 0; i < BPL; ++i) c[i] = a[ln * BPL + i];
    int s = 0;
#pragma unroll
    for (int i = 0; i < BPL; ++i) s += c[i];
    int run = s;
#pragma unroll
    for (int d = 1; d < 64; d <<= 1) {
        const int u = __shfl_up(run, d, 64);
        if (ln >= d) run += u;
    }
    int acc = run - s;
#pragma unroll
    for (int i = 0; i < BPL; ++i) { const int t = acc; acc += c[i]; a[ln * BPL + i] = t; }
    if (ln == 63) a[NB] = run;                   // total (= N)
}

// ---- 32-lane-group float scans over NB buckets (in place, 8 buckets/lane) ----
__device__ __forceinline__ void gscan_pre(float* a, int gl) {  // exclusive prefix
    float c[BPG];
#pragma unroll
    for (int i = 0; i < BPG; ++i) c[i] = a[gl * BPG + i];
    float s = 0.0f;
#pragma unroll
    for (int i = 0; i < BPG; ++i) s += c[i];
    float run = s;
#pragma unroll
    for (int d = 1; d < 32; d <<= 1) {
        const float u = __shfl_up(run, d, 32);
        if (gl >= d) run += u;
    }
    float acc = run - s;                         // sum over lanes < gl
#pragma unroll
    for (int i = 0; i < BPG; ++i) { const float t = acc; acc += c[i]; a[gl * BPG + i] = t; }
}
__device__ __forceinline__ void gscan_suf(float* a, int gl) {  // inclusive suffix
    float c[BPG];
#pragma unroll
    for (int i = 0; i < BPG; ++i) c[i] = a[gl * BPG + i];
    float s = 0.0f;
#pragma unroll
    for (int i = 0; i < BPG; ++i) s += c[i];
    float run = s;
#pragma unroll
    for (int d = 1; d < 32; d <<= 1) {
        const float u = __shfl_down(run, d, 32);
        if (gl < 32 - d) run += u;
    }
    float acc = run - s;                         // sum over lanes > gl
#pragma unroll
    for (int i = BPG - 1; i >= 0; --i) { acc += c[i]; a[gl * BPG + i] = acc; }
    // a[NB] zeroed separately (bucket-sum phase sentinels)
}

__global__ __launch_bounds__(NT) void gat_fused(
    const float* __restrict__ x,    // (32,1024,4)
    const float* __restrict__ W1,   // (3,4,2)
    const float* __restrict__ a1,   // (3,4)
    const float* __restrict__ W2,   // (6,4)
    const float* __restrict__ a2,   // (8)
    float* __restrict__ out)        // (32,1024,4)
{
    __shared__ __align__(16) float smem[SMEM_WORDS];
    __shared__ int   cs2[WCS];      // L2 counts/starts (not aliased)
    __shared__ float sMM[4][2 * NW];

    const int b   = blockIdx.x;
    const int tid = threadIdx.x, wv = tid >> 6, ln = tid & 63;
    const int hw  = tid >> 5, gl = tid & 31;    // 32-lane scan groups
    const int m   = tid;            // one element / one row per thread

    // ---- uniform weights ----
    float Wl1[3][4][2], as1[3][2], ad1[3][2];
#pragma unroll
    for (int hh = 0; hh < 3; ++hh) {
#pragma unroll
        for (int f = 0; f < 4; ++f)
#pragma unroll
            for (int o = 0; o < 2; ++o) Wl1[hh][f][o] = W1[(hh * 4 + f) * 2 + o];
#pragma unroll
        for (int o = 0; o < 2; ++o) {
            as1[hh][o] = a1[hh * 4 + o];
            ad1[hh][o] = a1[hh * 4 + 2 + o];
        }
    }
    float Wl2[6][4], as2[4], ad2[4];
#pragma unroll
    for (int f = 0; f < 6; ++f)
#pragma unroll
        for (int o = 0; o < 4; ++o) Wl2[f][o] = W2[f * 4 + o];
#pragma unroll
    for (int o = 0; o < 4; ++o) { as2[o] = a2[o]; ad2[o] = a2[4 + o]; }

    // ---- zero count arrays (ints only; everything else is write-once) ----
    if (tid < WCS) {
#pragma unroll
        for (int hh = 0; hh < 3; ++hh) ((int*)(smem + hh * L1_HEAD))[tid] = 0;
        cs2[tid] = 0;
    }

    // ================= LAYER 1 =================
    // P1: Wh, key=s_dst, s_src (regs); per-head block min/max
    const float4 xr = ((const float4*)(x + (size_t)b * N * 4))[m];
    float key1[3], sn1[3], wh1[3][2];
#pragma unroll
    for (int hh = 0; hh < 3; ++hh) {
        const float w0 = xr.x * Wl1[hh][0][0] + xr.y * Wl1[hh][1][0] +
                         xr.z * Wl1[hh][2][0] + xr.w * Wl1[hh][3][0];
        const float w1 = xr.x * Wl1[hh][0][1] + xr.y * Wl1[hh][1][1] +
                         xr.z * Wl1[hh][2][1] + xr.w * Wl1[hh][3][1];
        wh1[hh][0] = w0; wh1[hh][1] = w1;
        key1[hh] = w0 * ad1[hh][0] + w1 * ad1[hh][1];
        sn1[hh]  = w0 * as1[hh][0] + w1 * as1[hh][1];
        float mn = key1[hh], mx = key1[hh];
#pragma unroll
        for (int d = 1; d < 64; d <<= 1) {
            mn = fminf(mn, __shfl_xor(mn, d, 64));
            mx = fmaxf(mx, __shfl_xor(mx, d, 64));
        }
        if (ln == 0) { sMM[hh][wv] = mn; sMM[hh][NW + wv] = mx; }
    }
    __syncthreads();   // bar 1: zeros + sMM

    float kmin1[3], invw1[3];
#pragma unroll
    for (int hh = 0; hh < 3; ++hh) {
        float mn = sMM[hh][0], mx = sMM[hh][NW];
#pragma unroll
        for (int w = 1; w < NW; ++w) {
            mn = fminf(mn, sMM[hh][w]);
            mx = fmaxf(mx, sMM[hh][NW + w]);
        }
        kmin1[hh] = mn;
        invw1[hh] = (float)NB / fmaxf(mx - mn, 1e-30f);
    }

    // P2: bucket + rank (native int LDS atomic only)
    int bk1[3], rk1[3];
#pragma unroll
    for (int hh = 0; hh < 3; ++hh) {
        int q = (int)((key1[hh] - kmin1[hh]) * invw1[hh]);
        q = q < 0 ? 0 : (q > NB - 1 ? NB - 1 : q);
        bk1[hh] = q;
        rk1[hh] = atomicAdd((int*)(smem + hh * L1_HEAD) + q, 1);
    }
    __syncthreads();   // bar 2

    // P3: int scans -> exclusive starts (3 one-wave jobs)
    if (wv < 3) wave_scan_int((int*)(smem + wv * L1_HEAD), ln);
    __syncthreads();   // bar 3

    // P4: rank-scatter values (key, wh0, wh1)
#pragma unroll
    for (int hh = 0; hh < 3; ++hh) {
        float* bp = smem + hh * L1_HEAD;
        const int pos = ((int*)bp)[bk1[hh]] + rk1[hh];
        bp[OFF_KEY + pos] = key1[hh];
        bp[OFF_WH0 + pos] = wh1[hh][0];
        bp[OFF_WH1 + pos] = wh1[hh][1];
    }
    __syncthreads();   // bar 4

    // P5: segmented reduce -> per-bucket sums (768 threads; non-atomic)
    if (tid < 3 * NB) {
        const int hh = tid >> 8, q = tid & (NB - 1);
        float* bp = smem + hh * L1_HEAD;
        const int i0 = ((const int*)bp)[q], i1 = ((const int*)bp)[q + 1];
        float se1 = 0.0f, se2 = 0.0f, se1w0 = 0.0f, se1w1 = 0.0f, se2w0 = 0.0f, se2w1 = 0.0f;
        for (int i = i0; i < i1; ++i) {
            const float k = bp[OFF_KEY + i];
            const float w0 = bp[OFF_WH0 + i], w1 = bp[OFF_WH1 + i];
            const float e1 = ex2(LOG2E * k);
            const float e2 = ex2(GAT_ALPHA * LOG2E * k);
            se1 += e1; se2 += e2;
            se1w0 += e1 * w0; se1w1 += e1 * w1;
            se2w0 += e2 * w0; se2w1 += e2 * w1;
        }
        bp[OFF_SUF + q] = se1;
        bp[OFF_SUF + WCS + q] = se1w0;
        bp[OFF_SUF + 2 * WCS + q] = se1w1;
        bp[OFF_PRE + q] = se2;
        bp[OFF_PRE + WCS + q] = se2w0;
        bp[OFF_PRE + 2 * WCS + q] = se2w1;
    }
    if (tid < 9) {     // suf[a][NB] = 0 sentinels (read at bq = NB-1)
        const int hh = tid / 3, a = tid % 3;
        (smem + hh * L1_HEAD)[OFF_SUF + a * WCS + NB] = 0.0f;
    }
    __syncthreads();   // bar 5

    // P6: in-place scans, 18 GROUP jobs (32 lanes each) -> ONE round
    if (hw < 18) {
        const int hh = hw / 6, r = hw % 6;
        float* bp = smem + hh * L1_HEAD;
        if (r < 3) gscan_pre(bp + OFF_PRE + r * WCS, gl);
        else       gscan_suf(bp + OFF_SUF + (r - 3) * WCS, gl);
    }
    __syncthreads();   // bar 6

    // P7: rows -> h1 (registers); L2 phase-1 folded in (sMM[3])
    float hv[6];
#pragma unroll
    for (int hh = 0; hh < 3; ++hh) {
        float* bp = smem + hh * L1_HEAD;
        const int* cs = (const int*)bp;
        const float sn = sn1[hh];
        const float rho = ex2(0.8f * LOG2E * sn);
        int bq = (int)((-sn - kmin1[hh]) * invw1[hh]);
        bq = bq < 0 ? 0 : (bq > NB - 1 ? NB - 1 : bq);
        const int i0 = cs[bq], i1 = cs[bq + 1];
        float den = rho * bp[OFF_SUF + bq + 1] + bp[OFF_PRE + bq];
        float n0  = rho * bp[OFF_SUF + WCS + bq + 1] + bp[OFF_PRE + WCS + bq];
        float n1  = rho * bp[OFF_SUF + 2 * WCS + bq + 1] + bp[OFF_PRE + 2 * WCS + bq];
        for (int i = i0; i < i1; ++i) {          // boundary bucket: exact max-form
            const float kk = bp[OFF_KEY + i];
            const float w = fmaxf(rho * ex2(LOG2E * kk), ex2(GAT_ALPHA * LOG2E * kk));
            den += w;
            n0 += w * bp[OFF_WH0 + i];
            n1 += w * bp[OFF_WH1 + i];
        }
        float v0 = n0 / den, v1 = n1 / den;
        hv[hh * 2]     = (v0 > 0.0f) ? v0 : (__expf(v0) - 1.0f);
        hv[hh * 2 + 1] = (v1 > 0.0f) ? v1 : (__expf(v1) - 1.0f);
    }
    // L2 P1: wh2/key2/sn2 from register h1 + minmax
    float key2, sn2, wh2[4];
    {
        float kd = 0.0f, sn = 0.0f;
#pragma unroll
        for (int o = 0; o < 4; ++o) {
            float acc = 0.0f;
#pragma unroll
            for (int f = 0; f < 6; ++f) acc += hv[f] * Wl2[f][o];
            wh2[o] = acc;
            kd += acc * ad2[o];
            sn += acc * as2[o];
        }
        key2 = kd; sn2 = sn;
        float mn = kd, mx = kd;
#pragma unroll
        for (int d = 1; d < 64; d <<= 1) {
            mn = fminf(mn, __shfl_xor(mn, d, 64));
            mx = fmaxf(mx, __shfl_xor(mx, d, 64));
        }
        if (ln == 0) { sMM[3][wv] = mn; sMM[3][NW + wv] = mx; }
    }
    __syncthreads();   // bar 7: L1 arrays dead; sMM[3] ready; cs2 pre-zeroed

    // ================= LAYER 2 (aliased; h1 register-only) =================
    float kmin2, invw2;
    {
        float mn = sMM[3][0], mx = sMM[3][NW];
#pragma unroll
        for (int w = 1; w < NW; ++w) {
            mn = fminf(mn, sMM[3][w]);
            mx = fmaxf(mx, sMM[3][NW + w]);
        }
        kmin2 = mn;
        invw2 = (float)NB / fmaxf(mx - mn, 1e-30f);
    }

    // P2': bucket + rank
    int bk2, rk2;
    {
        int q = (int)((key2 - kmin2) * invw2);
        q = q < 0 ? 0 : (q > NB - 1 ? NB - 1 : q);
        bk2 = q;
        rk2 = atomicAdd(cs2 + q, 1);
    }
    __syncthreads();   // bar 8

    // P3': int scan
    if (wv == 0) wave_scan_int(cs2, ln);
    __syncthreads();   // bar 9

    // P4': scatter key + wh
    {
        const int pos = cs2[bk2] + rk2;
        smem[OFF2_KEY + pos] = key2;
#pragma unroll
        for (int o = 0; o < 4; ++o) smem[OFF2_WHS + o * N + pos] = wh2[o];
    }
    __syncthreads();   // bar 10

    // P5': segmented reduce split by exp-family across 512 threads
    if (tid < 2 * NB) {
        const int q = tid & (NB - 1);
        const bool e1fam = tid < NB;
        const float esc = e1fam ? LOG2E : (GAT_ALPHA * LOG2E);
        const int i0 = cs2[q], i1 = cs2[q + 1];
        float s0 = 0.0f, s1 = 0.0f, s2 = 0.0f, s3 = 0.0f, s4 = 0.0f;
        for (int i = i0; i < i1; ++i) {
            const float e = ex2(esc * smem[OFF2_KEY + i]);
            s0 += e;
            s1 += e * smem[OFF2_WHS + 0 * N + i];
            s2 += e * smem[OFF2_WHS + 1 * N + i];
            s3 += e * smem[OFF2_WHS + 2 * N + i];
            s4 += e * smem[OFF2_WHS + 3 * N + i];
        }
        float* dst = e1fam ? (smem + OFF2_SUF) : (smem + OFF2_PRE);
        dst[q] = s0;
        dst[WCS + q] = s1;
        dst[2 * WCS + q] = s2;
        dst[3 * WCS + q] = s3;
        dst[4 * WCS + q] = s4;
    }
    if (tid >= 2 * NB && tid < 2 * NB + 5)      // suf2[a][NB] = 0 sentinels
        smem[OFF2_SUF + (tid - 2 * NB) * WCS + NB] = 0.0f;
    __syncthreads();   // bar 11

    // P6': in-place scans, 10 GROUP jobs -> one round
    if (hw < 10) {
        if (hw < 5) gscan_pre(smem + OFF2_PRE + hw * WCS, gl);
        else        gscan_suf(smem + OFF2_SUF + (hw - 5) * WCS, gl);
    }
    __syncthreads();   // bar 12

    // P7': rows -> out (float4)
    {
        const float rho = ex2(0.8f * LOG2E * sn2);
        int bq = (int)((-sn2 - kmin2) * invw2);
        bq = bq < 0 ? 0 : (bq > NB - 1 ? NB - 1 : bq);
        const int i0 = cs2[bq], i1 = cs2[bq + 1];
        float den = rho * smem[OFF2_SUF + bq + 1] + smem[OFF2_PRE + bq];
        float num[4];
#pragma unroll
        for (int o = 0; o < 4; ++o)
            num[o] = rho * smem[OFF2_SUF + (1 + o) * WCS + bq + 1] +
                     smem[OFF2_PRE + (1 + o) * WCS + bq];
        for (int i = i0; i < i1; ++i) {          // boundary bucket: exact max-form
            const float kk = smem[OFF2_KEY + i];
            const float w = fmaxf(rho * ex2(LOG2E * kk), ex2(GAT_ALPHA * LOG2E * kk));
            den += w;
#pragma unroll
            for (int o = 0; o < 4; ++o) num[o] += w * smem[OFF2_WHS + o * N + i];
        }
        float vv[4];
#pragma unroll
        for (int o = 0; o < 4; ++o) {
            float v = num[o] / den;
            vv[o] = (v > 0.0f) ? v : (__expf(v) - 1.0f);
        }
        float4 yv;
        yv.x = vv[0]; yv.y = vv[1]; yv.z = vv[2]; yv.w = vv[3];
        ((float4*)out)[(size_t)b * N + m] = yv;
    }
}

extern "C" void kernel_launch(void* const* d_in, const int* in_sizes, int n_in,
                              void* d_out, int out_size, void* d_ws, size_t ws_size,
                              hipStream_t stream) {
    const float* x  = (const float*)d_in[0];  // (32,1024,4)
    const float* W1 = (const float*)d_in[1];  // (3,4,2)
    const float* a1 = (const float*)d_in[2];  // (3,4,1)
    const float* W2 = (const float*)d_in[3];  // (1,6,4)
    const float* a2 = (const float*)d_in[4];  // (1,8,1)
    float* y = (float*)d_out;                 // (32,1024,4)

    (void)d_ws; (void)ws_size;
    gat_fused<<<32, NT, 0, stream>>>(x, W1, a1, W2, a2, y);
}